// Round 5
// baseline (611.520 us; speedup 1.0000x reference)
//
#include <hip/hip_runtime.h>
#include <hip/hip_bf16.h>

#define N_TOK 2048
#define HIDDEN 1024
#define NHEAD 16
#define DHEAD 64

typedef __attribute__((ext_vector_type(8))) short bf16x8;
typedef __attribute__((ext_vector_type(4))) float f32x4;

__device__ inline unsigned short f2bf(float x) {
    __hip_bfloat16 h = __float2bfloat16(x);
    return *reinterpret_cast<unsigned short*>(&h);
}

__device__ inline f32x4 zero4() {
    f32x4 z;
    z[0] = 0.f; z[1] = 0.f; z[2] = 0.f; z[3] = 0.f;
    return z;
}

// ---------------- K0: fused f32 -> bf16 conversion for x, Wq, Wk, Wv ----------------
__global__ void cvt4_kernel(const float* __restrict__ x, const float* __restrict__ wq,
                            const float* __restrict__ wk, const float* __restrict__ wv,
                            unsigned short* __restrict__ dst) {
    int i = blockIdx.x * blockDim.x + threadIdx.x;  // 1310720 float4 jobs
    const float* src;
    int off;
    if (i < 524288)       { src = x;  off = i; }
    else if (i < 786432)  { src = wq; off = i - 524288; }
    else if (i < 1048576) { src = wk; off = i - 786432; }
    else                  { src = wv; off = i - 1048576; }
    float4 v = reinterpret_cast<const float4*>(src)[off];
    ushort4 o;
    o.x = f2bf(v.x); o.y = f2bf(v.y); o.z = f2bf(v.z); o.w = f2bf(v.w);
    reinterpret_cast<ushort4*>(dst)[i] = o;
}

// ---------------- K1: fused QKV GEMM (double-buffered, reg-prefetch) ----------------
__launch_bounds__(256)
__global__ void gemm_qkv(const unsigned short* __restrict__ xb,
                         const unsigned short* __restrict__ wb,
                         const float* __restrict__ bq, const float* __restrict__ bk,
                         const float* __restrict__ bv,
                         unsigned short* __restrict__ qb, unsigned short* __restrict__ kb,
                         unsigned short* __restrict__ vb) {
    __shared__ unsigned short As[2][128 * 64];
    __shared__ unsigned short Bs[2][128 * 64];
    const int tid = threadIdx.x;
    const int lane = tid & 63;
    const int w = tid >> 6;
    const int wr = w >> 1, wc = w & 1;
    const int rb = blockIdx.y * 128;
    const int cb = blockIdx.x * 128;
    const int r0 = tid >> 3, c0 = tid & 7;

    f32x4 acc[4][4];
    for (int i = 0; i < 4; i++)
        for (int j = 0; j < 4; j++) acc[i][j] = zero4();

    uint4 va[4], vb4[4];
#pragma unroll
    for (int i = 0; i < 4; i++) {
        va[i]  = *reinterpret_cast<const uint4*>(xb + (size_t)(rb + r0 + 32 * i) * HIDDEN + c0 * 8);
        vb4[i] = *reinterpret_cast<const uint4*>(wb + (size_t)(cb + r0 + 32 * i) * HIDDEN + c0 * 8);
    }
#pragma unroll
    for (int i = 0; i < 4; i++) {
        int row = r0 + 32 * i;
        *reinterpret_cast<uint4*>(As[0] + row * 64 + ((c0 ^ (row & 7)) << 3)) = va[i];
        *reinterpret_cast<uint4*>(Bs[0] + row * 64 + ((c0 ^ (row & 7)) << 3)) = vb4[i];
    }
    __syncthreads();
    int cur = 0;

    for (int kt = 0; kt < 16; ++kt) {
        if (kt < 15) {
#pragma unroll
            for (int i = 0; i < 4; i++) {
                va[i]  = *reinterpret_cast<const uint4*>(xb + (size_t)(rb + r0 + 32 * i) * HIDDEN + (kt + 1) * 64 + c0 * 8);
                vb4[i] = *reinterpret_cast<const uint4*>(wb + (size_t)(cb + r0 + 32 * i) * HIDDEN + (kt + 1) * 64 + c0 * 8);
            }
        }
#pragma unroll
        for (int kk = 0; kk < 2; kk++) {
            bf16x8 a[4], b[4];
#pragma unroll
            for (int mi = 0; mi < 4; mi++) {
                int row = wr * 64 + mi * 16 + (lane & 15);
                a[mi] = *reinterpret_cast<const bf16x8*>(As[cur] + row * 64 + (((kk * 4 + (lane >> 4)) ^ (row & 7)) << 3));
            }
#pragma unroll
            for (int ni = 0; ni < 4; ni++) {
                int row = wc * 64 + ni * 16 + (lane & 15);
                b[ni] = *reinterpret_cast<const bf16x8*>(Bs[cur] + row * 64 + (((kk * 4 + (lane >> 4)) ^ (row & 7)) << 3));
            }
#pragma unroll
            for (int mi = 0; mi < 4; mi++)
#pragma unroll
                for (int ni = 0; ni < 4; ni++)
                    acc[mi][ni] = __builtin_amdgcn_mfma_f32_16x16x32_bf16(a[mi], b[ni], acc[mi][ni], 0, 0, 0);
        }
        if (kt < 15) {
#pragma unroll
            for (int i = 0; i < 4; i++) {
                int row = r0 + 32 * i;
                *reinterpret_cast<uint4*>(As[cur ^ 1] + row * 64 + ((c0 ^ (row & 7)) << 3)) = va[i];
                *reinterpret_cast<uint4*>(Bs[cur ^ 1] + row * 64 + ((c0 ^ (row & 7)) << 3)) = vb4[i];
            }
        }
        __syncthreads();
        cur ^= 1;
    }

    const int region = blockIdx.x >> 3;  // 0=q, 1=k, 2=v
    const float* bias = region == 0 ? bq : (region == 1 ? bk : bv);
    unsigned short* dst = region == 0 ? qb : (region == 1 ? kb : vb);
#pragma unroll
    for (int mi = 0; mi < 4; mi++) {
#pragma unroll
        for (int ni = 0; ni < 4; ni++) {
            int colg = cb + wc * 64 + ni * 16 + (lane & 15);
            int jj = colg & 1023;
            int hh = jj >> 6, d = jj & 63;
            float bval = bias[jj];
#pragma unroll
            for (int r = 0; r < 4; r++) {
                int n = rb + wr * 64 + mi * 16 + ((lane >> 4) << 2) + r;
                dst[((size_t)hh * N_TOK + n) * 64 + d] = f2bf(acc[mi][ni][r] + bval);
            }
        }
    }
}

// ---------------- K1b: transpose v [h][n][d] -> vbt [h][d][n] ----------------
__global__ void transpose_v(const unsigned short* __restrict__ vb, unsigned short* __restrict__ vbt) {
    int t = blockIdx.x * blockDim.x + threadIdx.x;
    int nc = t & 255, d = (t >> 8) & 63, h = t >> 14;
    int n0 = nc * 8;
    unsigned short tmp[8];
#pragma unroll
    for (int j = 0; j < 8; j++)
        tmp[j] = vb[((size_t)h * N_TOK + n0 + j) * 64 + d];
    *reinterpret_cast<uint4*>(vbt + ((size_t)h * 64 + d) * N_TOK + n0) = *reinterpret_cast<uint4*>(tmp);
}

// ---------------- K2a: stats — barrier-free, K frags direct from L2 ----------------
__launch_bounds__(256)
__global__ void attn_stats(const unsigned short* __restrict__ qb,
                           const unsigned short* __restrict__ kb,
                           const float* __restrict__ hist,
                           const float* __restrict__ beta_p,
                           float* __restrict__ m_part,
                           float* __restrict__ l_part) {
    const int tid = threadIdx.x;
    const int lane = tid & 63;
    const int g = lane >> 4;
    const int q15 = lane & 15;
    const int w = tid >> 6;
    const int chunk = blockIdx.x;
    const int rb = blockIdx.y;
    const int h = blockIdx.z;
    const int n0 = rb * 64;
    const int c_base = chunk * 512;
    const float beta = beta_p[0];
    const float scale = 0.125f;
    const int qrow = w * 16 + q15;

    const unsigned short* qsrc = qb + ((size_t)h * N_TOK + n0 + qrow) * 64;
    bf16x8 aq0 = *reinterpret_cast<const bf16x8*>(qsrc + 8 * g);
    bf16x8 aq1 = *reinterpret_cast<const bf16x8*>(qsrc + 8 * g + 32);

    // K fragment base: row (c + nt*16 + q15), byte offset 16g (+32 for kk=1)
    const unsigned short* kfb = kb + ((size_t)h * N_TOK + c_base + q15) * 64 + 8 * g;

    float m = -1e30f, l = 0.0f;
    const float* hbase = hist + ((size_t)h * N_TOK + n0 + qrow) * N_TOK + c_base + 4 * g;

    for (int t = 0; t < 8; t++) {
        f32x4 h4[4];
#pragma unroll
        for (int nt = 0; nt < 4; nt++)
            h4[nt] = *reinterpret_cast<const f32x4*>(hbase + t * 64 + nt * 16);

        f32x4 s_acc[4];
#pragma unroll
        for (int nt = 0; nt < 4; nt++) {
            const unsigned short* kr = kfb + (size_t)(t * 64 + nt * 16) * 64;
            bf16x8 kf0 = *reinterpret_cast<const bf16x8*>(kr);
            bf16x8 kf1 = *reinterpret_cast<const bf16x8*>(kr + 32);
            s_acc[nt] = __builtin_amdgcn_mfma_f32_16x16x32_bf16(kf0, aq0, zero4(), 0, 0, 0);
            s_acc[nt] = __builtin_amdgcn_mfma_f32_16x16x32_bf16(kf1, aq1, s_acc[nt], 0, 0, 0);
        }
        float sc[4][4];
#pragma unroll
        for (int nt = 0; nt < 4; nt++)
#pragma unroll
            for (int r = 0; r < 4; r++)
                sc[nt][r] = s_acc[nt][r] * scale + beta * h4[nt][r];

        float tm = sc[0][0];
#pragma unroll
        for (int nt = 0; nt < 4; nt++)
#pragma unroll
            for (int r = 0; r < 4; r++) tm = fmaxf(tm, sc[nt][r]);
        tm = fmaxf(tm, __shfl_xor(tm, 16));
        tm = fmaxf(tm, __shfl_xor(tm, 32));
        float mn = fmaxf(m, tm);
        float ps = 0.0f;
#pragma unroll
        for (int nt = 0; nt < 4; nt++)
#pragma unroll
            for (int r = 0; r < 4; r++) ps += __expf(sc[nt][r] - mn);
        ps += __shfl_xor(ps, 16);
        ps += __shfl_xor(ps, 32);
        l = l * __expf(m - mn) + ps;
        m = mn;
    }

    if (lane < 16) {
        const int base = ((h * 32 + rb) * 4 + chunk) * 64;
        m_part[base + w * 16 + lane] = m;
        l_part[base + w * 16 + lane] = l;
    }
}

// ---------------- K2b: finalize — barrier-free; K/V frags from L2; NT output stores ----------------
__launch_bounds__(256)
__global__ void attn_finalize(const unsigned short* __restrict__ qb,
                              const unsigned short* __restrict__ kb,
                              const unsigned short* __restrict__ vbt,
                              const float* __restrict__ hist,
                              const float* __restrict__ beta_p,
                              const float* __restrict__ m_part,
                              const float* __restrict__ l_part,
                              float* __restrict__ attn_out,
                              float* __restrict__ nh_out,
                              float* __restrict__ opart) {
    __shared__ unsigned short Ps[4][16 * 64];  // per-wave P repack tile (no barrier needed)
    const int tid = threadIdx.x;
    const int lane = tid & 63;
    const int g = lane >> 4;
    const int q15 = lane & 15;
    const int w = tid >> 6;
    const int chunk = blockIdx.x;
    const int rb = blockIdx.y;
    const int h = blockIdx.z;
    const int n0 = rb * 64;
    const int c_base = chunk * 512;
    const float beta = beta_p[0];
    const float scale = 0.125f;
    const int qrow = w * 16 + q15;

    const unsigned short* qsrc = qb + ((size_t)h * N_TOK + n0 + qrow) * 64;
    bf16x8 aq0 = *reinterpret_cast<const bf16x8*>(qsrc + 8 * g);
    bf16x8 aq1 = *reinterpret_cast<const bf16x8*>(qsrc + 8 * g + 32);

    float m_row, inv_l;
    {
        const int pbase = (h * 32 + rb) * 4 * 64;
        float m0 = m_part[pbase + 0 * 64 + qrow];
        float m1 = m_part[pbase + 1 * 64 + qrow];
        float m2 = m_part[pbase + 2 * 64 + qrow];
        float m3 = m_part[pbase + 3 * 64 + qrow];
        float mm = fmaxf(fmaxf(m0, m1), fmaxf(m2, m3));
        float ll = l_part[pbase + 0 * 64 + qrow] * __expf(m0 - mm)
                 + l_part[pbase + 1 * 64 + qrow] * __expf(m1 - mm)
                 + l_part[pbase + 2 * 64 + qrow] * __expf(m2 - mm)
                 + l_part[pbase + 3 * 64 + qrow] * __expf(m3 - mm);
        m_row = mm;
        inv_l = 1.0f / ll;
    }

    f32x4 oacc[4];
#pragma unroll
    for (int di = 0; di < 4; di++) oacc[di] = zero4();

    unsigned short* Psw = Ps[w];
    const unsigned short* kfb = kb + ((size_t)h * N_TOK + c_base + q15) * 64 + 8 * g;
    // V^T fragment base: row (d = di*16 + q15), col c_base + 32*kk2 + 8*g
    const unsigned short* vfb = vbt + ((size_t)h * 64 + q15) * N_TOK + c_base + 8 * g;
    const float* hbase = hist + ((size_t)h * N_TOK + n0 + qrow) * N_TOK + c_base + 4 * g;
    float* abase = attn_out + ((size_t)h * N_TOK + n0 + qrow) * N_TOK + c_base + 4 * g;
    float* nbase = nh_out + ((size_t)h * N_TOK + n0 + qrow) * N_TOK + c_base + 4 * g;

    for (int t = 0; t < 8; t++) {
        f32x4 h4[4];
#pragma unroll
        for (int nt = 0; nt < 4; nt++)
            h4[nt] = *reinterpret_cast<const f32x4*>(hbase + t * 64 + nt * 16);

        f32x4 s_acc[4];
#pragma unroll
        for (int nt = 0; nt < 4; nt++) {
            const unsigned short* kr = kfb + (size_t)(t * 64 + nt * 16) * 64;
            bf16x8 kf0 = *reinterpret_cast<const bf16x8*>(kr);
            bf16x8 kf1 = *reinterpret_cast<const bf16x8*>(kr + 32);
            s_acc[nt] = __builtin_amdgcn_mfma_f32_16x16x32_bf16(kf0, aq0, zero4(), 0, 0, 0);
            s_acc[nt] = __builtin_amdgcn_mfma_f32_16x16x32_bf16(kf1, aq1, s_acc[nt], 0, 0, 0);
        }

#pragma unroll
        for (int nt = 0; nt < 4; nt++) {
            float a0 = __expf(s_acc[nt][0] * scale + beta * h4[nt][0] - m_row) * inv_l;
            float a1 = __expf(s_acc[nt][1] * scale + beta * h4[nt][1] - m_row) * inv_l;
            float a2 = __expf(s_acc[nt][2] * scale + beta * h4[nt][2] - m_row) * inv_l;
            float a3 = __expf(s_acc[nt][3] * scale + beta * h4[nt][3] - m_row) * inv_l;
            f32x4 av, nv;
            av[0] = a0; av[1] = a1; av[2] = a2; av[3] = a3;
            nv[0] = a0 + h4[nt][0]; nv[1] = a1 + h4[nt][1];
            nv[2] = a2 + h4[nt][2]; nv[3] = a3 + h4[nt][3];
            __builtin_nontemporal_store(av, reinterpret_cast<f32x4*>(abase + t * 64 + nt * 16));
            __builtin_nontemporal_store(nv, reinterpret_cast<f32x4*>(nbase + t * 64 + nt * 16));
            ushort4 p;
            p.x = f2bf(a0); p.y = f2bf(a1); p.z = f2bf(a2); p.w = f2bf(a3);
            *reinterpret_cast<ushort4*>(Psw + q15 * 64 + (((4 * nt + g) ^ (q15 & 14)) << 2)) = p;
        }

#pragma unroll
        for (int kk2 = 0; kk2 < 2; kk2++) {
            bf16x8 pa = *reinterpret_cast<const bf16x8*>(Psw + q15 * 64 + (((8 * kk2 + 2 * g) ^ (q15 & 14)) << 2));
#pragma unroll
            for (int di = 0; di < 4; di++) {
                const unsigned short* vr = vfb + (size_t)(di * 16) * N_TOK + t * 64 + 32 * kk2;
                bf16x8 vf = *reinterpret_cast<const bf16x8*>(vr);
                oacc[di] = __builtin_amdgcn_mfma_f32_16x16x32_bf16(pa, vf, oacc[di], 0, 0, 0);
            }
        }
    }

#pragma unroll
    for (int di = 0; di < 4; di++) {
#pragma unroll
        for (int r = 0; r < 4; r++) {
            int rl = w * 16 + g * 4 + r;
            int d = di * 16 + q15;
            opart[((size_t)(chunk * NHEAD + h) * N_TOK + n0 + rl) * 64 + d] = oacc[di][r];
        }
    }
}

// ---------------- K2c: reduce PV partials ----------------
__global__ void reduce_hv(const float4* __restrict__ op, float4* __restrict__ hv) {
    size_t i = (size_t)blockIdx.x * blockDim.x + threadIdx.x;
    const size_t C = (size_t)NHEAD * N_TOK * DHEAD / 4;
    float4 a = op[i], b = op[i + C], c = op[i + 2 * C], d = op[i + 3 * C];
    float4 r;
    r.x = a.x + b.x + c.x + d.x;
    r.y = a.y + b.y + c.y + d.y;
    r.z = a.z + b.z + c.z + d.z;
    r.w = a.w + b.w + c.w + d.w;
    hv[i] = r;
}

// ---------------- K3: output projection ----------------
__launch_bounds__(256)
__global__ void out_proj(const float* __restrict__ hv, const float* __restrict__ Wo,
                         const float* __restrict__ bo, float* __restrict__ out) {
    __shared__ float wos[64][129];
    const int tid = threadIdx.x;
    const int dd = tid & 63;
    const int w = tid >> 6;
    const int n0 = blockIdx.x * 16;
    float acc[4] = {0.f, 0.f, 0.f, 0.f};
    for (int kc = 0; kc < 1024; kc += 128) {
        __syncthreads();
#pragma unroll
        for (int i = 0; i < 32; i++) {
            int e = tid + 256 * i;
            int r = e >> 7, j = e & 127;
            wos[r][j] = Wo[(size_t)r * 1024 + kc + j];
        }
        __syncthreads();
#pragma unroll 4
        for (int k = 0; k < 128; k++) {
            float wv = wos[dd][k];
            int jg = kc + k;
            const float* hb = hv + ((size_t)(jg >> 6) * N_TOK) * 64 + (jg & 63);
#pragma unroll
            for (int q = 0; q < 4; q++) {
                acc[q] += hb[(size_t)(n0 + w + 4 * q) * 64] * wv;
            }
        }
    }
#pragma unroll
    for (int q = 0; q < 4; q++)
        out[(size_t)(n0 + w + 4 * q) * 64 + dd] = acc[q] + bo[dd];
}

extern "C" void kernel_launch(void* const* d_in, const int* in_sizes, int n_in,
                              void* d_out, int out_size, void* d_ws, size_t ws_size,
                              hipStream_t stream) {
    const float* x    = (const float*)d_in[0];
    const float* hist = (const float*)d_in[1];
    const float* Wq_w = (const float*)d_in[2];
    const float* Wq_b = (const float*)d_in[3];
    const float* Wk_w = (const float*)d_in[4];
    const float* Wk_b = (const float*)d_in[5];
    const float* Wv_w = (const float*)d_in[6];
    const float* Wv_b = (const float*)d_in[7];
    const float* Wo_w = (const float*)d_in[8];
    const float* Wo_b = (const float*)d_in[9];
    const float* beta = (const float*)d_in[10];

    float* out = (float*)d_out;
    float* attn_out = out + 131072;
    float* nh_out = attn_out + (size_t)NHEAD * N_TOK * N_TOK;

    unsigned short* xb  = (unsigned short*)d_ws;                 // 2M shorts
    unsigned short* wb  = xb + (size_t)N_TOK * HIDDEN;           // 3M shorts
    unsigned short* qb  = wb + (size_t)3 * HIDDEN * HIDDEN;      // 2M
    unsigned short* kb  = qb + (size_t)N_TOK * HIDDEN;
    unsigned short* vb  = kb + (size_t)N_TOK * HIDDEN;
    unsigned short* vbt = vb + (size_t)N_TOK * HIDDEN;
    float* hvb    = (float*)(vbt + (size_t)N_TOK * HIDDEN);      // 2M f32
    float* m_part = hvb + (size_t)N_TOK * HIDDEN;                // 128K f32
    float* l_part = m_part + 16 * 32 * 4 * 64;                   // 128K f32
    float* opart  = l_part + 16 * 32 * 4 * 64;                   // 8M f32 (32MB)

    cvt4_kernel<<<5120, 256, 0, stream>>>(x, Wq_w, Wk_w, Wv_w, xb);
    gemm_qkv<<<dim3(24, 16), 256, 0, stream>>>(xb, wb, Wq_b, Wk_b, Wv_b, qb, kb, vb);
    transpose_v<<<1024, 256, 0, stream>>>(vb, vbt);
    attn_stats<<<dim3(4, 32, 16), 256, 0, stream>>>(qb, kb, hist, beta, m_part, l_part);
    attn_finalize<<<dim3(4, 32, 16), 256, 0, stream>>>(qb, kb, vbt, hist, beta, m_part, l_part,
                                                       attn_out, nh_out, opart);
    reduce_hv<<<2048, 256, 0, stream>>>((const float4*)opart, (float4*)hvb);
    out_proj<<<128, 256, 0, stream>>>(hvb, Wo_w, Wo_b, out);
}

// Round 6
// 550.278 us; speedup vs baseline: 1.1113x; 1.1113x over previous
//
#include <hip/hip_runtime.h>
#include <hip/hip_bf16.h>

#define N_TOK 2048
#define HIDDEN 1024
#define NHEAD 16
#define DHEAD 64

typedef __attribute__((ext_vector_type(8))) short bf16x8;
typedef __attribute__((ext_vector_type(4))) float f32x4;

__device__ inline unsigned short f2bf(float x) {
    __hip_bfloat16 h = __float2bfloat16(x);
    return *reinterpret_cast<unsigned short*>(&h);
}

__device__ inline f32x4 zero4() {
    f32x4 z;
    z[0] = 0.f; z[1] = 0.f; z[2] = 0.f; z[3] = 0.f;
    return z;
}

// ---------------- K0: fused f32 -> bf16 conversion for x, Wq, Wk, Wv ----------------
__global__ void cvt4_kernel(const float* __restrict__ x, const float* __restrict__ wq,
                            const float* __restrict__ wk, const float* __restrict__ wv,
                            unsigned short* __restrict__ dst) {
    int i = blockIdx.x * blockDim.x + threadIdx.x;  // 1310720 float4 jobs
    const float* src;
    int off;
    if (i < 524288)       { src = x;  off = i; }
    else if (i < 786432)  { src = wq; off = i - 524288; }
    else if (i < 1048576) { src = wk; off = i - 786432; }
    else                  { src = wv; off = i - 1048576; }
    float4 v = reinterpret_cast<const float4*>(src)[off];
    ushort4 o;
    o.x = f2bf(v.x); o.y = f2bf(v.y); o.z = f2bf(v.z); o.w = f2bf(v.w);
    reinterpret_cast<ushort4*>(dst)[i] = o;
}

// ---------------- K1: fused QKV GEMM (double-buffered, reg-prefetch) ----------------
__launch_bounds__(256)
__global__ void gemm_qkv(const unsigned short* __restrict__ xb,
                         const unsigned short* __restrict__ wb,
                         const float* __restrict__ bq, const float* __restrict__ bk,
                         const float* __restrict__ bv,
                         unsigned short* __restrict__ qb, unsigned short* __restrict__ kb,
                         unsigned short* __restrict__ vb) {
    __shared__ unsigned short As[2][128 * 64];
    __shared__ unsigned short Bs[2][128 * 64];
    const int tid = threadIdx.x;
    const int lane = tid & 63;
    const int w = tid >> 6;
    const int wr = w >> 1, wc = w & 1;
    const int rb = blockIdx.y * 128;
    const int cb = blockIdx.x * 128;
    const int r0 = tid >> 3, c0 = tid & 7;

    f32x4 acc[4][4];
    for (int i = 0; i < 4; i++)
        for (int j = 0; j < 4; j++) acc[i][j] = zero4();

    uint4 va[4], vb4[4];
#pragma unroll
    for (int i = 0; i < 4; i++) {
        va[i]  = *reinterpret_cast<const uint4*>(xb + (size_t)(rb + r0 + 32 * i) * HIDDEN + c0 * 8);
        vb4[i] = *reinterpret_cast<const uint4*>(wb + (size_t)(cb + r0 + 32 * i) * HIDDEN + c0 * 8);
    }
#pragma unroll
    for (int i = 0; i < 4; i++) {
        int row = r0 + 32 * i;
        *reinterpret_cast<uint4*>(As[0] + row * 64 + ((c0 ^ (row & 7)) << 3)) = va[i];
        *reinterpret_cast<uint4*>(Bs[0] + row * 64 + ((c0 ^ (row & 7)) << 3)) = vb4[i];
    }
    __syncthreads();
    int cur = 0;

    for (int kt = 0; kt < 16; ++kt) {
        if (kt < 15) {
#pragma unroll
            for (int i = 0; i < 4; i++) {
                va[i]  = *reinterpret_cast<const uint4*>(xb + (size_t)(rb + r0 + 32 * i) * HIDDEN + (kt + 1) * 64 + c0 * 8);
                vb4[i] = *reinterpret_cast<const uint4*>(wb + (size_t)(cb + r0 + 32 * i) * HIDDEN + (kt + 1) * 64 + c0 * 8);
            }
        }
#pragma unroll
        for (int kk = 0; kk < 2; kk++) {
            bf16x8 a[4], b[4];
#pragma unroll
            for (int mi = 0; mi < 4; mi++) {
                int row = wr * 64 + mi * 16 + (lane & 15);
                a[mi] = *reinterpret_cast<const bf16x8*>(As[cur] + row * 64 + (((kk * 4 + (lane >> 4)) ^ (row & 7)) << 3));
            }
#pragma unroll
            for (int ni = 0; ni < 4; ni++) {
                int row = wc * 64 + ni * 16 + (lane & 15);
                b[ni] = *reinterpret_cast<const bf16x8*>(Bs[cur] + row * 64 + (((kk * 4 + (lane >> 4)) ^ (row & 7)) << 3));
            }
#pragma unroll
            for (int mi = 0; mi < 4; mi++)
#pragma unroll
                for (int ni = 0; ni < 4; ni++)
                    acc[mi][ni] = __builtin_amdgcn_mfma_f32_16x16x32_bf16(a[mi], b[ni], acc[mi][ni], 0, 0, 0);
        }
        if (kt < 15) {
#pragma unroll
            for (int i = 0; i < 4; i++) {
                int row = r0 + 32 * i;
                *reinterpret_cast<uint4*>(As[cur ^ 1] + row * 64 + ((c0 ^ (row & 7)) << 3)) = va[i];
                *reinterpret_cast<uint4*>(Bs[cur ^ 1] + row * 64 + ((c0 ^ (row & 7)) << 3)) = vb4[i];
            }
        }
        __syncthreads();
        cur ^= 1;
    }

    const int region = blockIdx.x >> 3;  // 0=q, 1=k, 2=v
    const float* bias = region == 0 ? bq : (region == 1 ? bk : bv);
    unsigned short* dst = region == 0 ? qb : (region == 1 ? kb : vb);
#pragma unroll
    for (int mi = 0; mi < 4; mi++) {
#pragma unroll
        for (int ni = 0; ni < 4; ni++) {
            int colg = cb + wc * 64 + ni * 16 + (lane & 15);
            int jj = colg & 1023;
            int hh = jj >> 6, d = jj & 63;
            float bval = bias[jj];
#pragma unroll
            for (int r = 0; r < 4; r++) {
                int n = rb + wr * 64 + mi * 16 + ((lane >> 4) << 2) + r;
                dst[((size_t)hh * N_TOK + n) * 64 + d] = f2bf(acc[mi][ni][r] + bval);
            }
        }
    }
}

// ---------------- K1b: transpose v [h][n][d] -> tiled vt [h][tile][d][64] ----------------
__global__ void transpose_v(const unsigned short* __restrict__ vb, unsigned short* __restrict__ vt) {
    int t = blockIdx.x * blockDim.x + threadIdx.x;
    int nc = t & 255, d = (t >> 8) & 63, h = t >> 14;
    int n0 = nc * 8;
    unsigned short tmp[8];
#pragma unroll
    for (int j = 0; j < 8; j++)
        tmp[j] = vb[((size_t)h * N_TOK + n0 + j) * 64 + d];
    // tiled: vt[((h*32 + tile)*64 + d)*64 + colInTile]
    size_t dsti = (((size_t)(h * 32 + (nc >> 3)) * 64 + d) * 64) + (nc & 7) * 8;
    *reinterpret_cast<uint4*>(vt + dsti) = *reinterpret_cast<uint4*>(tmp);
}

// ---------------- K2: fused attention — 1 wave/block, zero barriers ----------------
// grid (rb=128, h=16): 16 q-rows per block, all 2048 cols, two passes (stats, emit).
// Wave-private LDS staging (in-order DS => no __syncthreads anywhere).
__launch_bounds__(64, 2)
__global__ void attn_fused(const unsigned short* __restrict__ qb,
                           const unsigned short* __restrict__ kb,
                           const unsigned short* __restrict__ vt,
                           const float* __restrict__ hist,
                           const float* __restrict__ beta_p,
                           float* __restrict__ attn_out,
                           float* __restrict__ nh_out,
                           float* __restrict__ hv) {
    __shared__ unsigned short Ks[64 * 64];
    __shared__ unsigned short Vs[64 * 64];
    __shared__ unsigned short Ps[16 * 64];
    const int lane = threadIdx.x;
    const int g = lane >> 4, q15 = lane & 15;
    const int jr8 = lane >> 3, jc = lane & 7;
    const int rb = blockIdx.x, h = blockIdx.y;
    const float beta = beta_p[0];
    const float scale = 0.125f;

    const unsigned short* qsrc = qb + ((size_t)h * N_TOK + rb * 16 + q15) * 64;
    bf16x8 aq0 = *reinterpret_cast<const bf16x8*>(qsrc + 8 * g);
    bf16x8 aq1 = *reinterpret_cast<const bf16x8*>(qsrc + 8 * g + 32);

    const unsigned short* kt0 = kb + (size_t)h * N_TOK * 64;       // + t*4096
    const unsigned short* vt0 = vt + (size_t)h * 32 * 4096;        // + t*4096
    const float* hbase = hist + ((size_t)h * N_TOK + rb * 16 + q15) * N_TOK + 4 * g;
    float* abase = attn_out + ((size_t)h * N_TOK + rb * 16 + q15) * N_TOK + 4 * g;
    float* nbase = nh_out + ((size_t)h * N_TOK + rb * 16 + q15) * N_TOK + 4 * g;

    float m = -1e30f, l = 0.0f;
    f32x4 h4[4], h4n[4];

    // ---- pass 1 prologue: stage K tile 0 + hist tile 0 ----
    {
        uint4 kr[8];
#pragma unroll
        for (int i = 0; i < 8; i++)
            kr[i] = *reinterpret_cast<const uint4*>(kt0 + (size_t)(i * 8 + jr8) * 64 + jc * 8);
#pragma unroll
        for (int i = 0; i < 8; i++) {
            int row = i * 8 + jr8;
            *reinterpret_cast<uint4*>(Ks + row * 64 + ((jc ^ (row & 7)) << 3)) = kr[i];
        }
#pragma unroll
        for (int nt = 0; nt < 4; nt++) h4[nt] = *reinterpret_cast<const f32x4*>(hbase + nt * 16);
    }

    // ---- pass 1: stats ----
    for (int t = 0; t < 32; t++) {
        uint4 kn[8];
        if (t < 31) {
#pragma unroll
            for (int i = 0; i < 8; i++)
                kn[i] = *reinterpret_cast<const uint4*>(kt0 + (size_t)(t + 1) * 4096 + (size_t)(i * 8 + jr8) * 64 + jc * 8);
#pragma unroll
            for (int nt = 0; nt < 4; nt++)
                h4n[nt] = *reinterpret_cast<const f32x4*>(hbase + (t + 1) * 64 + nt * 16);
        }
        f32x4 s_acc[4];
#pragma unroll
        for (int nt = 0; nt < 4; nt++) {
            int krow = nt * 16 + q15;
            bf16x8 kf0 = *reinterpret_cast<const bf16x8*>(Ks + krow * 64 + ((g ^ (q15 & 7)) << 3));
            bf16x8 kf1 = *reinterpret_cast<const bf16x8*>(Ks + krow * 64 + (((4 + g) ^ (q15 & 7)) << 3));
            s_acc[nt] = __builtin_amdgcn_mfma_f32_16x16x32_bf16(kf0, aq0, zero4(), 0, 0, 0);
            s_acc[nt] = __builtin_amdgcn_mfma_f32_16x16x32_bf16(kf1, aq1, s_acc[nt], 0, 0, 0);
        }
        float sc[4][4];
#pragma unroll
        for (int nt = 0; nt < 4; nt++)
#pragma unroll
            for (int r = 0; r < 4; r++)
                sc[nt][r] = s_acc[nt][r] * scale + beta * h4[nt][r];

        float tm = sc[0][0];
#pragma unroll
        for (int nt = 0; nt < 4; nt++)
#pragma unroll
            for (int r = 0; r < 4; r++) tm = fmaxf(tm, sc[nt][r]);
        tm = fmaxf(tm, __shfl_xor(tm, 16));
        tm = fmaxf(tm, __shfl_xor(tm, 32));
        float mn = fmaxf(m, tm);
        float ps = 0.0f;
#pragma unroll
        for (int nt = 0; nt < 4; nt++)
#pragma unroll
            for (int r = 0; r < 4; r++) ps += __expf(sc[nt][r] - mn);
        ps += __shfl_xor(ps, 16);
        ps += __shfl_xor(ps, 32);
        l = l * __expf(m - mn) + ps;
        m = mn;

        if (t < 31) {
#pragma unroll
            for (int i = 0; i < 8; i++) {
                int row = i * 8 + jr8;
                *reinterpret_cast<uint4*>(Ks + row * 64 + ((jc ^ (row & 7)) << 3)) = kn[i];
            }
#pragma unroll
            for (int nt = 0; nt < 4; nt++) h4[nt] = h4n[nt];
        }
    }
    const float inv_l = 1.0f / l;

    f32x4 oacc[4];
#pragma unroll
    for (int di = 0; di < 4; di++) oacc[di] = zero4();

    // ---- pass 2 prologue: K tile 31 still staged; stage V tile 31 + hist tile 31 ----
    {
        uint4 vr[8];
#pragma unroll
        for (int i = 0; i < 8; i++)
            vr[i] = *reinterpret_cast<const uint4*>(vt0 + (size_t)31 * 4096 + (size_t)(i * 8 + jr8) * 64 + jc * 8);
#pragma unroll
        for (int i = 0; i < 8; i++) {
            int row = i * 8 + jr8;
            *reinterpret_cast<uint4*>(Vs + row * 64 + ((jc ^ (row & 7)) << 3)) = vr[i];
        }
#pragma unroll
        for (int nt = 0; nt < 4; nt++)
            h4[nt] = *reinterpret_cast<const f32x4*>(hbase + 31 * 64 + nt * 16);
    }

    // ---- pass 2: emit attn/nh + PV, reverse tile order for L2/L3 hist reuse ----
    for (int tt = 0; tt < 32; tt++) {
        const int t = 31 - tt;
        uint4 kn[8], vn[8];
        if (tt < 31) {
#pragma unroll
            for (int i = 0; i < 8; i++) {
                kn[i] = *reinterpret_cast<const uint4*>(kt0 + (size_t)(t - 1) * 4096 + (size_t)(i * 8 + jr8) * 64 + jc * 8);
                vn[i] = *reinterpret_cast<const uint4*>(vt0 + (size_t)(t - 1) * 4096 + (size_t)(i * 8 + jr8) * 64 + jc * 8);
            }
#pragma unroll
            for (int nt = 0; nt < 4; nt++)
                h4n[nt] = *reinterpret_cast<const f32x4*>(hbase + (t - 1) * 64 + nt * 16);
        }

        f32x4 s_acc[4];
#pragma unroll
        for (int nt = 0; nt < 4; nt++) {
            int krow = nt * 16 + q15;
            bf16x8 kf0 = *reinterpret_cast<const bf16x8*>(Ks + krow * 64 + ((g ^ (q15 & 7)) << 3));
            bf16x8 kf1 = *reinterpret_cast<const bf16x8*>(Ks + krow * 64 + (((4 + g) ^ (q15 & 7)) << 3));
            s_acc[nt] = __builtin_amdgcn_mfma_f32_16x16x32_bf16(kf0, aq0, zero4(), 0, 0, 0);
            s_acc[nt] = __builtin_amdgcn_mfma_f32_16x16x32_bf16(kf1, aq1, s_acc[nt], 0, 0, 0);
        }

#pragma unroll
        for (int nt = 0; nt < 4; nt++) {
            float a0 = __expf(s_acc[nt][0] * scale + beta * h4[nt][0] - m) * inv_l;
            float a1 = __expf(s_acc[nt][1] * scale + beta * h4[nt][1] - m) * inv_l;
            float a2 = __expf(s_acc[nt][2] * scale + beta * h4[nt][2] - m) * inv_l;
            float a3 = __expf(s_acc[nt][3] * scale + beta * h4[nt][3] - m) * inv_l;
            f32x4 av, nv;
            av[0] = a0; av[1] = a1; av[2] = a2; av[3] = a3;
            nv[0] = a0 + h4[nt][0]; nv[1] = a1 + h4[nt][1];
            nv[2] = a2 + h4[nt][2]; nv[3] = a3 + h4[nt][3];
            __builtin_nontemporal_store(av, reinterpret_cast<f32x4*>(abase + t * 64 + nt * 16));
            __builtin_nontemporal_store(nv, reinterpret_cast<f32x4*>(nbase + t * 64 + nt * 16));
            ushort4 p;
            p.x = f2bf(a0); p.y = f2bf(a1); p.z = f2bf(a2); p.w = f2bf(a3);
            *reinterpret_cast<ushort4*>(Ps + q15 * 64 + (((4 * nt + g) ^ (q15 & 14)) << 2)) = p;
        }

#pragma unroll
        for (int kk2 = 0; kk2 < 2; kk2++) {
            bf16x8 pa = *reinterpret_cast<const bf16x8*>(Ps + q15 * 64 + (((8 * kk2 + 2 * g) ^ (q15 & 14)) << 2));
#pragma unroll
            for (int di = 0; di < 4; di++) {
                int vrow = di * 16 + q15;
                bf16x8 vf = *reinterpret_cast<const bf16x8*>(Vs + vrow * 64 + (((kk2 * 4 + g) ^ (q15 & 7)) << 3));
                oacc[di] = __builtin_amdgcn_mfma_f32_16x16x32_bf16(pa, vf, oacc[di], 0, 0, 0);
            }
        }

        if (tt < 31) {
#pragma unroll
            for (int i = 0; i < 8; i++) {
                int row = i * 8 + jr8;
                *reinterpret_cast<uint4*>(Ks + row * 64 + ((jc ^ (row & 7)) << 3)) = kn[i];
                *reinterpret_cast<uint4*>(Vs + row * 64 + ((jc ^ (row & 7)) << 3)) = vn[i];
            }
#pragma unroll
            for (int nt = 0; nt < 4; nt++) h4[nt] = h4n[nt];
        }
    }

    // epilogue: hv write (complete over all cols — no partials/reduce needed)
#pragma unroll
    for (int di = 0; di < 4; di++) {
#pragma unroll
        for (int r = 0; r < 4; r++) {
            int rl = g * 4 + r;
            int d = di * 16 + q15;
            hv[((size_t)h * N_TOK + rb * 16 + rl) * 64 + d] = oacc[di][r];
        }
    }
}

// ---------------- K3: output projection ----------------
__launch_bounds__(256)
__global__ void out_proj(const float* __restrict__ hv, const float* __restrict__ Wo,
                         const float* __restrict__ bo, float* __restrict__ out) {
    __shared__ float wos[64][129];
    const int tid = threadIdx.x;
    const int dd = tid & 63;
    const int w = tid >> 6;
    const int n0 = blockIdx.x * 16;
    float acc[4] = {0.f, 0.f, 0.f, 0.f};
    for (int kc = 0; kc < 1024; kc += 128) {
        __syncthreads();
#pragma unroll
        for (int i = 0; i < 32; i++) {
            int e = tid + 256 * i;
            int r = e >> 7, j = e & 127;
            wos[r][j] = Wo[(size_t)r * 1024 + kc + j];
        }
        __syncthreads();
#pragma unroll 4
        for (int k = 0; k < 128; k++) {
            float wv = wos[dd][k];
            int jg = kc + k;
            const float* hb = hv + ((size_t)(jg >> 6) * N_TOK) * 64 + (jg & 63);
#pragma unroll
            for (int q = 0; q < 4; q++) {
                acc[q] += hb[(size_t)(n0 + w + 4 * q) * 64] * wv;
            }
        }
    }
#pragma unroll
    for (int q = 0; q < 4; q++)
        out[(size_t)(n0 + w + 4 * q) * 64 + dd] = acc[q] + bo[dd];
}

extern "C" void kernel_launch(void* const* d_in, const int* in_sizes, int n_in,
                              void* d_out, int out_size, void* d_ws, size_t ws_size,
                              hipStream_t stream) {
    const float* x    = (const float*)d_in[0];
    const float* hist = (const float*)d_in[1];
    const float* Wq_w = (const float*)d_in[2];
    const float* Wq_b = (const float*)d_in[3];
    const float* Wk_w = (const float*)d_in[4];
    const float* Wk_b = (const float*)d_in[5];
    const float* Wv_w = (const float*)d_in[6];
    const float* Wv_b = (const float*)d_in[7];
    const float* Wo_w = (const float*)d_in[8];
    const float* Wo_b = (const float*)d_in[9];
    const float* beta = (const float*)d_in[10];

    float* out = (float*)d_out;
    float* attn_out = out + 131072;
    float* nh_out = attn_out + (size_t)NHEAD * N_TOK * N_TOK;

    unsigned short* xb  = (unsigned short*)d_ws;                 // 2M shorts
    unsigned short* wb  = xb + (size_t)N_TOK * HIDDEN;           // 3M shorts
    unsigned short* qb  = wb + (size_t)3 * HIDDEN * HIDDEN;      // 2M
    unsigned short* kb  = qb + (size_t)N_TOK * HIDDEN;
    unsigned short* vb  = kb + (size_t)N_TOK * HIDDEN;
    unsigned short* vt  = vb + (size_t)N_TOK * HIDDEN;
    float* hvb = (float*)(vt + (size_t)N_TOK * HIDDEN);          // 2M f32

    cvt4_kernel<<<5120, 256, 0, stream>>>(x, Wq_w, Wk_w, Wv_w, xb);
    gemm_qkv<<<dim3(24, 16), 256, 0, stream>>>(xb, wb, Wq_b, Wk_b, Wv_b, qb, kb, vb);
    transpose_v<<<1024, 256, 0, stream>>>(vb, vt);
    attn_fused<<<dim3(128, 16), 64, 0, stream>>>(qb, kb, vt, hist, beta,
                                                 attn_out, nh_out, hvb);
    out_proj<<<128, 256, 0, stream>>>(hvb, Wo_w, Wo_b, out);
}